// Round 16
// baseline (189.837 us; speedup 1.0000x reference)
//
#include <hip/hip_runtime.h>

// ---------------------------------------------------------------------------
// SelfAttention (dual cross-attention): B=4, S=1024, HID=1024, NH=16, DH=64
//   q1,k1,v1,q2,k2,v2 = x @ W*.T + b*   (bf16 MFMA, f32 accum)
//   out5 = attn(q1,k2,v2), out3 = attn(q2,k1,v1)
// ---------------------------------------------------------------------------

typedef __attribute__((ext_vector_type(8))) short bf16x8;
typedef __attribute__((ext_vector_type(4))) short bf16x4;
typedef __attribute__((ext_vector_type(4))) float f32x4;
typedef __attribute__((ext_vector_type(4))) short s16x4;

#define MFMA16(a, b, c) __builtin_amdgcn_mfma_f32_16x16x32_bf16(a, b, c, 0, 0, 0)
#define BARRIER() asm volatile("s_barrier" ::: "memory")
#define VMCNT0() asm volatile("s_waitcnt vmcnt(0)" ::: "memory")
#define VMCNT4() asm volatile("s_waitcnt vmcnt(4)" ::: "memory")

__device__ __forceinline__ f32x4 mfma16k(bf16x4 a, bf16x4 b, f32x4 c) {
#if __has_builtin(__builtin_amdgcn_mfma_f32_16x16x16bf16_1k)
  return __builtin_amdgcn_mfma_f32_16x16x16bf16_1k(a, b, c, 0, 0, 0);
#elif __has_builtin(__builtin_amdgcn_mfma_f32_16x16x16_bf16)
  return __builtin_amdgcn_mfma_f32_16x16x16_bf16(a, b, c, 0, 0, 0);
#else
  asm volatile("v_mfma_f32_16x16x16_bf16 %0, %1, %2, %0"
               : "+v"(c) : "v"(a), "v"(b));
  return c;
#endif
}

__device__ __forceinline__ unsigned short f2bf(float f) {
  unsigned u = __float_as_uint(f);
  u = (u + 0x7fffu + ((u >> 16) & 1u)) >> 16;  // RNE
  return (unsigned short)u;
}

__device__ __forceinline__ unsigned cvt_pk_bf16(float lo, float hi) {
  unsigned r;
  asm("v_cvt_pk_bf16_f32 %0, %1, %2" : "=v"(r) : "v"(lo), "v"(hi));
  return r;
}

__device__ __forceinline__ void gll16(const void* g, void* l) {
  __builtin_amdgcn_global_load_lds(
      (const __attribute__((address_space(1))) unsigned int*)g,
      (__attribute__((address_space(3))) unsigned int*)l, 16, 0, 0);
}

// ---------------------------------------------------------------------------
// Kernel 1: f32 -> bf16 conversion of x (4M) and the 6 weight matrices (6x1M)
// ---------------------------------------------------------------------------
__global__ __launch_bounds__(256) void convert_k(
    const float* __restrict__ x,
    const float* __restrict__ W0, const float* __restrict__ W1,
    const float* __restrict__ W2, const float* __restrict__ W3,
    const float* __restrict__ W4, const float* __restrict__ W5,
    short* __restrict__ xbf, short* __restrict__ wbf) {
  const int tid = blockIdx.x * 256 + threadIdx.x;
  const int e = tid << 2;
  const float* src;
  short* dst;
  int off;
  if (e < (4 << 20)) {
    src = x; dst = xbf; off = e;
  } else {
    const int j = e - (4 << 20);
    const int wsel = j >> 20;
    off = j & ((1 << 20) - 1);
    src = (wsel == 0) ? W0 : (wsel == 1) ? W1 : (wsel == 2) ? W2
        : (wsel == 3) ? W3 : (wsel == 4) ? W4 : W5;
    dst = wbf + ((size_t)wsel << 20);
  }
  const float4 v = *(const float4*)(src + off);
  s16x4 o;
  o.x = (short)f2bf(v.x);
  o.y = (short)f2bf(v.y);
  o.z = (short)f2bf(v.z);
  o.w = (short)f2bf(v.w);
  *(s16x4*)(dst + off) = o;
}

// ---------------------------------------------------------------------------
// Kernel 2: projection GEMM — m201-faithful 8-phase 256x256, BK=64, 512 thr
// (8 waves 2Mx4N), counted vmcnt pipeline (T3+T4, never tried with fenced
// barriers before). Phase = BLOCK-level C-quadrant (mh,nh) so each phase
// reads exactly one A-half (mh) + one B-half (nh) — halves free per-phase.
// Snake order (0,0)(0,1)(1,1)(1,0): 24 ds_read_b128/K-tile.
// Stage slots (tiles E=2j buf0, O=2j+1 buf1):
//   ph1: A1(O)+B0(O) | ph3: A0(E+2) | ph4: B1(E+2), vmcnt(4)
//   ph5: A1(E+2)+B0(E+2) | ph7: A0(E+3) | ph8: B1(E+3), vmcnt(4)
// Each vmcnt(4) leaves exactly the 2 newest half-stages (4 loads) in flight
// and certifies the tile read 1 phase later. Prologue: t0 full + t1{A0,B1},
// vmcnt(4). Tail j=7: ph4 vmcnt(0). WAR: every stage target's last ds_read
// is >=1 full barrier epoch earlier (audited per region).
// ---------------------------------------------------------------------------
__global__ __launch_bounds__(512, 2) void proj_g8(
    const short* __restrict__ Ag, const short* __restrict__ Wall,
    const float* __restrict__ bq, const float* __restrict__ bk,
    const float* __restrict__ bv, const float* __restrict__ bq2,
    const float* __restrict__ bk2, const float* __restrict__ bv2,
    short* __restrict__ qkv) {
  __shared__ __align__(16) short As[2][2][8192];  // [buf][half][128x64]
  __shared__ __align__(16) short Bs[2][2][8192];

  const int bid = blockIdx.x;             // 384
  const int xcd = bid & 7, i = bid >> 3;  // 48 per XCD
  const int nb = xcd * 3 + (i >> 4);      // 24 n-panels, 3 per XCD
  const int mb = i & 15;
  const int m0 = mb << 8;

  const int t = threadIdx.x, lane = t & 63, w = t >> 6;
  const int g = lane >> 4, lr = lane & 15;
  const int wr = w >> 2, wc = w & 3;      // 2M x 4N waves

  f32x4 acc[2][2][4][2] = {};  // [mh][nh][mi][nj]
  bf16x8 af[4][2], bf[2][2];   // persist across phases (snake reuse)

#define STAGE_A(T, H)                                                     \
  {                                                                       \
    const int k0s = (T) << 6;                                             \
    _Pragma("unroll") for (int ld = 0; ld < 2; ++ld) {                    \
      const int slot = (ld << 9) + t;                                     \
      const int rr = slot >> 3;                                           \
      const int gc = (slot & 7) ^ (rr & 7);                               \
      gll16(Ag + (size_t)(m0 + (H) * 128 + rr) * 1024 + k0s + (gc << 3),  \
            &As[(T) & 1][H][slot * 8]);                                   \
    }                                                                     \
  }
#define STAGE_B(T, H)                                                     \
  {                                                                       \
    const int k0s = (T) << 6;                                             \
    _Pragma("unroll") for (int ld = 0; ld < 2; ++ld) {                    \
      const int slot = (ld << 9) + t;                                     \
      const int rr = slot >> 3;                                           \
      const int gc = (slot & 7) ^ (rr & 7);                               \
      gll16(Wall + (size_t)((nb << 8) + (H) * 128 + rr) * 1024 + k0s +    \
                (gc << 3),                                                \
            &Bs[(T) & 1][H][slot * 8]);                                   \
    }                                                                     \
  }
#define LOAD_A(MH, TB)                                                    \
  _Pragma("unroll") for (int mi = 0; mi < 4; ++mi)                        \
    _Pragma("unroll") for (int kk = 0; kk < 2; ++kk) {                    \
      const int row = wr * 64 + mi * 16 + lr;                             \
      af[mi][kk] = *(const bf16x8*)                                       \
          &As[TB][MH][row * 64 + ((((kk << 2) + g) ^ (row & 7)) << 3)];   \
    }
#define LOAD_B(NH, TB)                                                    \
  _Pragma("unroll") for (int nj = 0; nj < 2; ++nj)                        \
    _Pragma("unroll") for (int kk = 0; kk < 2; ++kk) {                    \
      const int row = wc * 32 + nj * 16 + lr;                             \
      bf[nj][kk] = *(const bf16x8*)                                       \
          &Bs[TB][NH][row * 64 + ((((kk << 2) + g) ^ (row & 7)) << 3)];   \
    }
#define MFMA_PH(MH, NH)                                                   \
  __builtin_amdgcn_s_setprio(1);                                          \
  _Pragma("unroll") for (int mi = 0; mi < 4; ++mi)                        \
    _Pragma("unroll") for (int nj = 0; nj < 2; ++nj)                      \
      _Pragma("unroll") for (int kk = 0; kk < 2; ++kk)                    \
        acc[MH][NH][mi][nj] =                                             \
            MFMA16(af[mi][kk], bf[nj][kk], acc[MH][NH][mi][nj]);          \
  __builtin_amdgcn_s_setprio(0);

  // prologue: tile0 complete (8 loads) + tile1 {A0, B1} (4 loads)
  STAGE_A(0, 0); STAGE_A(0, 1); STAGE_B(0, 0); STAGE_B(0, 1);
  STAGE_A(1, 0); STAGE_B(1, 1);
  VMCNT4();  // certify tile0; t1{A0,B1} stay in flight
  BARRIER();

  for (int j = 0; j < 8; ++j) {
    const bool u = j < 7;
    { // ph1: E(mh0,nh0); stage A1(O)+B0(O)
      LOAD_A(0, 0); LOAD_B(0, 0);
      STAGE_A(2 * j + 1, 1); STAGE_B(2 * j + 1, 0);
      BARRIER(); MFMA_PH(0, 0); BARRIER();
    }
    { // ph2: E(mh0,nh1); reuse af
      LOAD_B(1, 0);
      BARRIER(); MFMA_PH(0, 1); BARRIER();
    }
    { // ph3: E(mh1,nh1); reuse bf; stage A0(E+2)
      LOAD_A(1, 0);
      if (u) STAGE_A(2 * j + 2, 0);
      BARRIER(); MFMA_PH(1, 1); BARRIER();
    }
    { // ph4: E(mh1,nh0); reuse af; stage B1(E+2); checkpoint -> tile O ready
      LOAD_B(0, 0);
      if (u) STAGE_B(2 * j + 2, 1);
      BARRIER(); MFMA_PH(1, 0);
      if (u) { VMCNT4(); } else { VMCNT0(); }
      BARRIER();
    }
    { // ph5: O(mh0,nh0); stage A1(E+2)+B0(E+2)
      LOAD_A(0, 1); LOAD_B(0, 1);
      if (u) { STAGE_A(2 * j + 2, 1); STAGE_B(2 * j + 2, 0); }
      BARRIER(); MFMA_PH(0, 0); BARRIER();
    }
    { // ph6: O(mh0,nh1)
      LOAD_B(1, 1);
      BARRIER(); MFMA_PH(0, 1); BARRIER();
    }
    { // ph7: O(mh1,nh1); stage A0(E+3)
      LOAD_A(1, 1);
      if (u) STAGE_A(2 * j + 3, 0);
      BARRIER(); MFMA_PH(1, 1); BARRIER();
    }
    { // ph8: O(mh1,nh0); stage B1(E+3); checkpoint -> tile E+2 ready
      LOAD_B(0, 1);
      if (u) STAGE_B(2 * j + 3, 1);
      BARRIER(); MFMA_PH(1, 0);
      if (u) { VMCNT4(); }
      BARRIER();
    }
  }

#undef STAGE_A
#undef STAGE_B
#undef LOAD_A
#undef LOAD_B
#undef MFMA_PH

  // ---- epilogue: bias + bf16 pack into attention layouts ----
#pragma unroll
  for (int nh = 0; nh < 2; ++nh) {
#pragma unroll
    for (int nj = 0; nj < 2; ++nj) {
      const int nn = (nb << 8) + nh * 128 + wc * 32 + nj * 16 + lr;
      const int p = nn >> 10, nl = nn & 1023;
      const float* bp = (p == 0) ? bq : (p == 1) ? bk : (p == 2) ? bv
                      : (p == 3) ? bq2 : (p == 4) ? bk2 : bv2;
      const float bb = bp[nl];
      const int h = nl >> 6, d = nl & 63;
      const int pt = (p == 0 || p == 3) ? 0 : (p == 1 || p == 4) ? 1 : 2;
      unsigned short* dst = (unsigned short*)qkv + ((size_t)p << 22);
#pragma unroll
      for (int mh = 0; mh < 2; ++mh) {
#pragma unroll
        for (int mi = 0; mi < 4; ++mi) {
#pragma unroll
          for (int r = 0; r < 4; ++r) {
            const int m = m0 + mh * 128 + wr * 64 + mi * 16 + (g << 2) + r;
            const int b = m >> 10, s = m & 1023;
            const unsigned short val = f2bf(acc[mh][nh][mi][nj][r] + bb);
            size_t idx;
            if (pt == 0) {
              idx = ((size_t)(((b << 4) + h) * 1024 + s) << 6) + d;
            } else if (pt == 1) {
              const int d2 = (d & 7) | (((d >> 3) ^ (s & 7)) << 3);
              idx = ((size_t)(((b << 4) + h) * 1024 + s) << 6) + d2;
            } else {
              const int tt = s >> 6, s2 = s & 63;
              const int s3 = (s2 & 7) | (((s2 >> 3) ^ (d & 7)) << 3);
              idx = ((size_t)((((b << 4) + h) * 16 + tt) * 64 + d) << 6) + s3;
            }
            dst[idx] = val;
          }
        }
      }
    }
  }
}

// ---------------------------------------------------------------------------
// Kernel 3: flash attention, swapped-QK^T in-register-P form; 128-row Q-tile
// (8 waves, 512 thr), double-buffered KV (32 KB -> 4 blocks/CU). r12-good.
// ---------------------------------------------------------------------------
__global__ __launch_bounds__(512) void attn_k(const short* __restrict__ qkv,
                                              float* __restrict__ out) {
  __shared__ __align__(16) short Ks[2][64 * 64];
  __shared__ __align__(16) short Vs[2][64 * 64];

  const int L = blockIdx.x;  // 1024 blocks
  const int xcd = L & 7, ss = L >> 3;   // ss 0..127
  const int qt = ss & 7, pg = ss >> 3;  // 8 q-tiles of 128 rows
  const int pp = xcd + (pg << 3);  // all q-tiles of a head share an XCD
  const int hb = pp & 63, dir = pp >> 6;

  const short* Q = qkv + ((size_t)(dir ? 3 : 0) << 22) + ((size_t)hb << 16);
  const short* K = qkv + ((size_t)(dir ? 1 : 4) << 22) + ((size_t)hb << 16);
  const short* V = qkv + ((size_t)(dir ? 2 : 5) << 22) + ((size_t)hb << 16);
  float* O = out + ((size_t)dir << 22);

  const int t = threadIdx.x, lane = t & 63, w = t >> 6;  // w 0..7
  const int g = lane >> 4, lr = lane & 15;

  const int qrow = (qt << 7) + (w << 4) + lr;
  bf16x8 qf[2];
  qf[0] = *(const bf16x8*)(Q + qrow * 64 + g * 8);
  qf[1] = *(const bf16x8*)(Q + qrow * 64 + 32 + g * 8);

  const bf16x4 ones4 = {0x3F80, 0x3F80, 0x3F80, 0x3F80};

  f32x4 oacc[4] = {};
  f32x4 lacc = {};
  float mrun = -3.0e38f;               // running max for q = lr (log2 units)
  const float CSC = 0.18033688f;       // (1/8) * log2(e)

  const int srow = t >> 3;             // staging row 0..63 (1 gll16/thread)
  const int scol = (t & 7) << 3;

  auto stage = [&](int kt, int buf) {
    gll16(K + (size_t)((kt << 6) + srow) * 64 + scol, &Ks[buf][w << 9]);
    gll16(V + (size_t)(kt << 12) + (size_t)srow * 64 + scol, &Vs[buf][w << 9]);
  };

  stage(0, 0);
  VMCNT0();
  BARRIER();

  int cur = 0;
  for (int kt = 0; kt < 16; ++kt) {
    if (kt < 15) stage(kt + 1, cur ^ 1);

    // ---- S^T = K Q^T (swapped): lane gets P^T[k=kn*16+g*4+r][q=lr] ----
    f32x4 sc2[4] = {};
    __builtin_amdgcn_s_setprio(1);
#pragma unroll
    for (int dk = 0; dk < 2; ++dk) {
#pragma unroll
      for (int kn = 0; kn < 4; ++kn) {
        const int krow = kn * 16 + lr;
        const bf16x8 kf = *(const bf16x8*)
            &Ks[cur][krow * 64 +
                     ((((dk << 6) + (g << 4)) ^ ((krow & 7) << 4)) >> 1)];
        sc2[kn] = MFMA16(kf, qf[dk], sc2[kn]);
      }
    }
    __builtin_amdgcn_s_setprio(0);

    // ---- softmax (per-lane scalar state, defer-max) ----
    float tm = fmaxf(fmaxf(fmaxf(sc2[0][0], sc2[0][1]),
                           fmaxf(sc2[0][2], sc2[0][3])),
                     fmaxf(fmaxf(sc2[1][0], sc2[1][1]),
                           fmaxf(sc2[1][2], sc2[1][3])));
    tm = fmaxf(tm, fmaxf(fmaxf(fmaxf(sc2[2][0], sc2[2][1]),
                               fmaxf(sc2[2][2], sc2[2][3])),
                         fmaxf(fmaxf(sc2[3][0], sc2[3][1]),
                               fmaxf(sc2[3][2], sc2[3][3]))));
    const bool ok = __all(fmaf(tm, CSC, -mrun) <= 8.0f);
    if (!ok) {
      float t2 = fmaxf(tm, __shfl_xor(tm, 16));
      t2 = fmaxf(t2, __shfl_xor(t2, 32));
      const float mnew = fmaxf(mrun, t2 * CSC);
      const float scq = exp2f(mrun - mnew);  // scale for q = lr
      mrun = mnew;
#pragma unroll
      for (int r = 0; r < 4; ++r) {
        const float sr = __shfl(scq, (g << 2) + r);  // scale for q = g*4+r
        lacc[r] *= sr;
#pragma unroll
        for (int dn = 0; dn < 4; ++dn) oacc[dn][r] *= sr;
      }
    }

    bf16x4 pa[4];
#pragma unroll
    for (int kn = 0; kn < 4; ++kn) {
      const float p0 = exp2f(fmaf(sc2[kn][0], CSC, -mrun));
      const float p1 = exp2f(fmaf(sc2[kn][1], CSC, -mrun));
      const float p2 = exp2f(fmaf(sc2[kn][2], CSC, -mrun));
      const float p3 = exp2f(fmaf(sc2[kn][3], CSC, -mrun));
      union { unsigned u[2]; bf16x4 v; } pk;
      pk.u[0] = cvt_pk_bf16(p0, p1);
      pk.u[1] = cvt_pk_bf16(p2, p3);
      pa[kn] = pk.v;
    }

    // ---- O += P V ; l += P @ ones  (K=16 MFMAs, P straight from regs) ----
    __builtin_amdgcn_s_setprio(1);
#pragma unroll
    for (int kn = 0; kn < 4; ++kn) {
      lacc = mfma16k(pa[kn], ones4, lacc);
#pragma unroll
      for (int dn = 0; dn < 4; ++dn) {
        const int vrow = dn * 16 + lr;
        const int ch = (2 * kn + (g >> 1)) ^ (vrow & 7);  // 16B-chunk swizzle
        const bf16x4 vf = *(const bf16x4*)
            &Vs[cur][vrow * 64 + ch * 8 + ((g & 1) << 2)];
        oacc[dn] = mfma16k(pa[kn], vf, oacc[dn]);
      }
    }
    __builtin_amdgcn_s_setprio(0);

    VMCNT0();
    BARRIER();
    cur ^= 1;
  }

  // ---- epilogue: out[b][q][h*64+d] = oacc / l ----
  const int b = hb >> 4, h = hb & 15;
  float rl[4];
#pragma unroll
  for (int r = 0; r < 4; ++r) rl[r] = 1.0f / lacc[r];
#pragma unroll
  for (int dn = 0; dn < 4; ++dn) {
#pragma unroll
    for (int r = 0; r < 4; ++r) {
      const int q = (qt << 7) + (w << 4) + (g << 2) + r;
      const int d = dn * 16 + lr;
      O[((size_t)(b * 1024 + q) << 10) + h * 64 + d] = oacc[dn][r] * rl[r];
    }
  }
}

// ---------------------------------------------------------------------------
extern "C" void kernel_launch(void* const* d_in, const int* in_sizes, int n_in,
                              void* d_out, int out_size, void* d_ws,
                              size_t ws_size, hipStream_t stream) {
  const float* x   = (const float*)d_in[0];
  const float* Wq  = (const float*)d_in[1];
  const float* bq  = (const float*)d_in[2];
  const float* Wk  = (const float*)d_in[3];
  const float* bk  = (const float*)d_in[4];
  const float* Wv  = (const float*)d_in[5];
  const float* bv  = (const float*)d_in[6];
  const float* Wq2 = (const float*)d_in[7];
  const float* bq2 = (const float*)d_in[8];
  const float* Wk2 = (const float*)d_in[9];
  const float* bk2 = (const float*)d_in[10];
  const float* Wv2 = (const float*)d_in[11];
  const float* bv2 = (const float*)d_in[12];

  char* ws = (char*)d_ws;
  short* xbf = (short*)ws;                      // 8 MB
  short* wbf = (short*)(ws + 8388608);          // 12 MB
  short* qkv = (short*)(ws + 20971520);         // 6 x 8 MB

  convert_k<<<10240, 256, 0, stream>>>(x, Wq, Wk, Wv, Wq2, Wk2, Wv2, xbf, wbf);
  proj_g8<<<384, 512, 0, stream>>>(xbf, wbf, bq, bk, bv, bq2, bk2,
                                   bv2, qkv);
  attn_k<<<1024, 512, 0, stream>>>(qkv, (float*)d_out);
}

// Round 17
// 153.024 us; speedup vs baseline: 1.2406x; 1.2406x over previous
//
#include <hip/hip_runtime.h>

// ---------------------------------------------------------------------------
// SelfAttention (dual cross-attention): B=4, S=1024, HID=1024, NH=16, DH=64
//   q1,k1,v1,q2,k2,v2 = x @ W*.T + b*   (bf16 MFMA, f32 accum)
//   out5 = attn(q1,k2,v2), out3 = attn(q2,k1,v1)
// ---------------------------------------------------------------------------

typedef __attribute__((ext_vector_type(8))) short bf16x8;
typedef __attribute__((ext_vector_type(4))) short bf16x4;
typedef __attribute__((ext_vector_type(4))) float f32x4;
typedef __attribute__((ext_vector_type(4))) short s16x4;

#define MFMA16(a, b, c) __builtin_amdgcn_mfma_f32_16x16x32_bf16(a, b, c, 0, 0, 0)
#define BARRIER() asm volatile("s_barrier" ::: "memory")
#define VMCNT0() asm volatile("s_waitcnt vmcnt(0)" ::: "memory")

__device__ __forceinline__ f32x4 mfma16k(bf16x4 a, bf16x4 b, f32x4 c) {
#if __has_builtin(__builtin_amdgcn_mfma_f32_16x16x16bf16_1k)
  return __builtin_amdgcn_mfma_f32_16x16x16bf16_1k(a, b, c, 0, 0, 0);
#elif __has_builtin(__builtin_amdgcn_mfma_f32_16x16x16_bf16)
  return __builtin_amdgcn_mfma_f32_16x16x16_bf16(a, b, c, 0, 0, 0);
#else
  asm volatile("v_mfma_f32_16x16x16_bf16 %0, %1, %2, %0"
               : "+v"(c) : "v"(a), "v"(b));
  return c;
#endif
}

__device__ __forceinline__ unsigned short f2bf(float f) {
  unsigned u = __float_as_uint(f);
  u = (u + 0x7fffu + ((u >> 16) & 1u)) >> 16;  // RNE
  return (unsigned short)u;
}

__device__ __forceinline__ unsigned cvt_pk_bf16(float lo, float hi) {
  unsigned r;
  asm("v_cvt_pk_bf16_f32 %0, %1, %2" : "=v"(r) : "v"(lo), "v"(hi));
  return r;
}

__device__ __forceinline__ void gll16(const void* g, void* l) {
  __builtin_amdgcn_global_load_lds(
      (const __attribute__((address_space(1))) unsigned int*)g,
      (__attribute__((address_space(3))) unsigned int*)l, 16, 0, 0);
}

// ---------------------------------------------------------------------------
// Kernel 1: f32 -> bf16 conversion of x (4M) and the 6 weight matrices
// (6x1M). Grid-stride over 2.62M float4 slots, 2048 blocks (G11).
// ---------------------------------------------------------------------------
__global__ __launch_bounds__(256) void convert_k(
    const float* __restrict__ x,
    const float* __restrict__ W0, const float* __restrict__ W1,
    const float* __restrict__ W2, const float* __restrict__ W3,
    const float* __restrict__ W4, const float* __restrict__ W5,
    short* __restrict__ xbf, short* __restrict__ wbf) {
  const int total = (10 << 20) >> 2;  // 2.62M vec4 slots
  for (int tid = blockIdx.x * 256 + threadIdx.x; tid < total;
       tid += 2048 * 256) {
    const int e = tid << 2;
    const float* src;
    short* dst;
    int off;
    if (e < (4 << 20)) {
      src = x; dst = xbf; off = e;
    } else {
      const int j = e - (4 << 20);
      const int wsel = j >> 20;
      off = j & ((1 << 20) - 1);
      src = (wsel == 0) ? W0 : (wsel == 1) ? W1 : (wsel == 2) ? W2
          : (wsel == 3) ? W3 : (wsel == 4) ? W4 : W5;
      dst = wbf + ((size_t)wsel << 20);
    }
    const float4 v = *(const float4*)(src + off);
    s16x4 o;
    o.x = (short)f2bf(v.x);
    o.y = (short)f2bf(v.y);
    o.z = (short)f2bf(v.z);
    o.w = (short)f2bf(v.w);
    *(s16x4*)(dst + off) = o;
  }
}

// ---------------------------------------------------------------------------
// Kernel 2: projection GEMM — round-12 version verbatim (best measured:
// 85.0 us). 256x192, BK=64, 512 thr (8 waves 2Mx4N, wave-tile 128x48),
// 2 phases/K-tile, fenced barriers, dribbled stage, vmcnt(0) certify.
// Grid 512 = 2 exact rounds. [4 attempts at deeper pipelines (8-phase,
// counted-vmcnt, TLP-first, 32x32) all regressed to 95-143 us — this
// simple 2-phase shape is the measured optimum of the family.]
// ---------------------------------------------------------------------------
__global__ __launch_bounds__(512, 2) void proj_gemm192(
    const short* __restrict__ Ag, const short* __restrict__ Wall,
    const float* __restrict__ bq, const float* __restrict__ bk,
    const float* __restrict__ bv, const float* __restrict__ bq2,
    const float* __restrict__ bk2, const float* __restrict__ bv2,
    short* __restrict__ qkv) {
  __shared__ __align__(16) short As[2][16384];  // 256 x 64
  __shared__ __align__(16) short Bs[2][12288];  // 192 x 64

  const int bid = blockIdx.x;            // 512
  const int xcd = bid & 7, k = bid >> 3; // 64 per XCD
  const int ns = k & 3, mb = k >> 2;     // 4 n-panels/XCD (1.5MB L2-hot)
  const int nbase = (xcd * 4 + ns) * 192;
  const int m0 = mb << 8;

  const int t = threadIdx.x, lane = t & 63, w = t >> 6;
  const int g = lane >> 4, lr = lane & 15;
  const int wr = w >> 2, wc = w & 3;     // 2M x 4N waves; wave C = 128x48

  f32x4 acc[2][4][3] = {};

  // stage helpers: linear LDS dest, inverse-chunk-swizzled global source
  auto stage_ah = [&](int T, int H) {  // A half H: rows H*128..+127, 2 instr
#pragma unroll
    for (int ld = 0; ld < 2; ++ld) {
      const int slot = (H << 10) + (ld << 9) + t;
      const int rr = slot >> 3;
      const int gc = (slot & 7) ^ (rr & 7);
      gll16(Ag + (size_t)(m0 + rr) * 1024 + (T << 6) + (gc << 3),
            &As[T & 1][slot * 8]);
    }
  };
  auto stage_b = [&](int T) {  // B 192 rows, 3 instr
#pragma unroll
    for (int ld = 0; ld < 3; ++ld) {
      const int slot = (ld << 9) + t;
      const int rr = slot >> 3;
      const int gc = (slot & 7) ^ (rr & 7);
      gll16(Wall + (size_t)(nbase + rr) * 1024 + (T << 6) + (gc << 3),
            &Bs[T & 1][slot * 8]);
    }
  };

  // prologue: tile 0 -> buf0
  stage_ah(0, 0); stage_ah(0, 1); stage_b(0);
  VMCNT0();
  BARRIER();

#define LOAD_A(AV, MH, KK, TB)                                            \
  _Pragma("unroll") for (int mi = 0; mi < 4; ++mi) {                      \
    const int rA = wr * 128 + (MH) * 64 + mi * 16 + lr;                   \
    AV[mi] = *(const bf16x8*)                                             \
        &As[TB][rA * 64 + ((((KK) * 4 + g) ^ (rA & 7)) << 3)];            \
  }
#define LOAD_B(KK, TB)                                                    \
  _Pragma("unroll") for (int nj = 0; nj < 3; ++nj) {                      \
    const int rB = wc * 48 + nj * 16 + lr;                                \
    bf[nj] = *(const bf16x8*)                                             \
        &Bs[TB][rB * 64 + ((((KK) * 4 + g) ^ (rB & 7)) << 3)];            \
  }
#define MFMA_MH(MH, AV)                                                   \
  _Pragma("unroll") for (int mi = 0; mi < 4; ++mi)                        \
    _Pragma("unroll") for (int nj = 0; nj < 3; ++nj)                      \
      acc[MH][mi][nj] = MFMA16(AV[mi], bf[nj], acc[MH][mi][nj]);

  // one 2-phase group: compute buf C (one K-tile), dribble tile TD (if DV)
  auto group = [&](int C, int TD, bool DV) {
    bf16x8 af0[4], af1[4], bf[3];
    { // phase 1: kk0 both mh (14 ds); dribble A-h0 + A-h1 (4 gll16)
      LOAD_A(af0, 0, 0, C); LOAD_A(af1, 1, 0, C); LOAD_B(0, C);
      if (DV) { stage_ah(TD, 0); stage_ah(TD, 1); }
      BARRIER();
      __builtin_amdgcn_s_setprio(1);
      MFMA_MH(0, af0);
      MFMA_MH(1, af1);
      __builtin_amdgcn_s_setprio(0);
      BARRIER();
    }
    { // phase 2: kk1 both mh (14 ds); dribble B (3 gll16); certify after MFMA
      LOAD_A(af0, 0, 1, C); LOAD_A(af1, 1, 1, C); LOAD_B(1, C);
      if (DV) stage_b(TD);
      BARRIER();
      __builtin_amdgcn_s_setprio(1);
      MFMA_MH(0, af0);
      MFMA_MH(1, af1);
      __builtin_amdgcn_s_setprio(0);
      VMCNT0();
      BARRIER();
    }
  };

  for (int j = 0; j < 8; ++j) {
    group(0, 2 * j + 1, true);
    group(1, 2 * j + 2, j < 7);
  }

#undef LOAD_A
#undef LOAD_B
#undef MFMA_MH

  // ---- epilogue: bias + bf16 pack into attention layouts (per-column p) ----
#pragma unroll
  for (int nj = 0; nj < 3; ++nj) {
    const int nn = nbase + wc * 48 + nj * 16 + lr;
    const int p = nn >> 10, nl = nn & 1023;
    const float* bp = (p == 0) ? bq : (p == 1) ? bk : (p == 2) ? bv
                    : (p == 3) ? bq2 : (p == 4) ? bk2 : bv2;
    const float bb = bp[nl];
    const int h = nl >> 6, d = nl & 63;
    const int pt = (p == 0 || p == 3) ? 0 : (p == 1 || p == 4) ? 1 : 2;
    unsigned short* dst = (unsigned short*)qkv + ((size_t)p << 22);
#pragma unroll
    for (int mh = 0; mh < 2; ++mh) {
#pragma unroll
      for (int mi = 0; mi < 4; ++mi) {
#pragma unroll
        for (int r = 0; r < 4; ++r) {
          const int m = m0 + wr * 128 + mh * 64 + mi * 16 + (g << 2) + r;
          const int b = m >> 10, s = m & 1023;
          const unsigned short val = f2bf(acc[mh][mi][nj][r] + bb);
          size_t idx;
          if (pt == 0) {
            idx = ((size_t)(((b << 4) + h) * 1024 + s) << 6) + d;
          } else if (pt == 1) {
            const int d2 = (d & 7) | (((d >> 3) ^ (s & 7)) << 3);
            idx = ((size_t)(((b << 4) + h) * 1024 + s) << 6) + d2;
          } else {
            const int tt = s >> 6, s2 = s & 63;
            const int s3 = (s2 & 7) | (((s2 >> 3) ^ (d & 7)) << 3);
            idx = ((size_t)((((b << 4) + h) * 16 + tt) * 64 + d) << 6) + s3;
          }
          dst[idx] = val;
        }
      }
    }
  }
}

// ---------------------------------------------------------------------------
// Kernel 3: flash attention, swapped-QK^T in-register-P form; 128-row Q-tile
// (8 waves, 512 thr), double-buffered KV (32 KB -> 4 blocks/CU).
// Round-17 change: KV loop explicitly unrolled x2 with LITERAL buffer
// indices (runtime `cur` forced per-access LDS address arithmetic; static
// 0/1 folds the buffer offset into ds_read immediates — rule-#20 analog).
// ---------------------------------------------------------------------------
__global__ __launch_bounds__(512) void attn_k(const short* __restrict__ qkv,
                                              float* __restrict__ out) {
  __shared__ __align__(16) short Ks[2][64 * 64];
  __shared__ __align__(16) short Vs[2][64 * 64];

  const int L = blockIdx.x;  // 1024 blocks
  const int xcd = L & 7, ss = L >> 3;   // ss 0..127
  const int qt = ss & 7, pg = ss >> 3;  // 8 q-tiles of 128 rows
  const int pp = xcd + (pg << 3);  // all q-tiles of a head share an XCD
  const int hb = pp & 63, dir = pp >> 6;

  const short* Q = qkv + ((size_t)(dir ? 3 : 0) << 22) + ((size_t)hb << 16);
  const short* K = qkv + ((size_t)(dir ? 1 : 4) << 22) + ((size_t)hb << 16);
  const short* V = qkv + ((size_t)(dir ? 2 : 5) << 22) + ((size_t)hb << 16);
  float* O = out + ((size_t)dir << 22);

  const int t = threadIdx.x, lane = t & 63, w = t >> 6;  // w 0..7
  const int g = lane >> 4, lr = lane & 15;

  const int qrow = (qt << 7) + (w << 4) + lr;
  bf16x8 qf[2];
  qf[0] = *(const bf16x8*)(Q + qrow * 64 + g * 8);
  qf[1] = *(const bf16x8*)(Q + qrow * 64 + 32 + g * 8);

  const bf16x4 ones4 = {0x3F80, 0x3F80, 0x3F80, 0x3F80};

  f32x4 oacc[4] = {};
  f32x4 lacc = {};
  float mrun = -3.0e38f;               // running max for q = lr (log2 units)
  const float CSC = 0.18033688f;       // (1/8) * log2(e)

  const int srow = t >> 3;             // staging row 0..63 (1 gll16/thread)
  const int scol = (t & 7) << 3;

  auto stage = [&](int kt, int buf) {
    gll16(K + (size_t)((kt << 6) + srow) * 64 + scol, &Ks[buf][w << 9]);
    gll16(V + (size_t)(kt << 12) + (size_t)srow * 64 + scol, &Vs[buf][w << 9]);
  };

  // one KV tile with compile-time buffer index CUR
  auto tile = [&](int kt, auto curc) {
    constexpr int CUR = decltype(curc)::value;
    if (kt < 15) stage(kt + 1, CUR ^ 1);

    // ---- S^T = K Q^T (swapped): lane gets P^T[k=kn*16+g*4+r][q=lr] ----
    f32x4 sc2[4] = {};
    __builtin_amdgcn_s_setprio(1);
#pragma unroll
    for (int dk = 0; dk < 2; ++dk) {
#pragma unroll
      for (int kn = 0; kn < 4; ++kn) {
        const int krow = kn * 16 + lr;
        const bf16x8 kf = *(const bf16x8*)
            &Ks[CUR][krow * 64 +
                     ((((dk << 6) + (g << 4)) ^ ((krow & 7) << 4)) >> 1)];
        sc2[kn] = MFMA16(kf, qf[dk], sc2[kn]);
      }
    }
    __builtin_amdgcn_s_setprio(0);

    // ---- softmax (per-lane scalar state, defer-max) ----
    float tm = fmaxf(fmaxf(fmaxf(sc2[0][0], sc2[0][1]),
                           fmaxf(sc2[0][2], sc2[0][3])),
                     fmaxf(fmaxf(sc2[1][0], sc2[1][1]),
                           fmaxf(sc2[1][2], sc2[1][3])));
    tm = fmaxf(tm, fmaxf(fmaxf(fmaxf(sc2[2][0], sc2[2][1]),
                               fmaxf(sc2[2][2], sc2[2][3])),
                         fmaxf(fmaxf(sc2[3][0], sc2[3][1]),
                               fmaxf(sc2[3][2], sc2[3][3]))));
    const bool ok = __all(fmaf(tm, CSC, -mrun) <= 8.0f);
    if (!ok) {
      float t2 = fmaxf(tm, __shfl_xor(tm, 16));
      t2 = fmaxf(t2, __shfl_xor(t2, 32));
      const float mnew = fmaxf(mrun, t2 * CSC);
      const float scq = exp2f(mrun - mnew);  // scale for q = lr
      mrun = mnew;
#pragma unroll
      for (int r = 0; r < 4; ++r) {
        const float sr = __shfl(scq, (g << 2) + r);  // scale for q = g*4+r
        lacc[r] *= sr;
#pragma unroll
        for (int dn = 0; dn < 4; ++dn) oacc[dn][r] *= sr;
      }
    }

    bf16x4 pa[4];
#pragma unroll
    for (int kn = 0; kn < 4; ++kn) {
      const float p0 = exp2f(fmaf(sc2[kn][0], CSC, -mrun));
      const float p1 = exp2f(fmaf(sc2[kn][1], CSC, -mrun));
      const float p2 = exp2f(fmaf(sc2[kn][2], CSC, -mrun));
      const float p3 = exp2f(fmaf(sc2[kn][3], CSC, -mrun));
      union { unsigned u[2]; bf16x4 v; } pk;
      pk.u[0] = cvt_pk_bf16(p0, p1);
      pk.u[1] = cvt_pk_bf16(p2, p3);
      pa[kn] = pk.v;
    }

    // ---- O += P V ; l += P @ ones  (K=16 MFMAs, P straight from regs) ----
    __builtin_amdgcn_s_setprio(1);
#pragma unroll
    for (int kn = 0; kn < 4; ++kn) {
      lacc = mfma16k(pa[kn], ones4, lacc);
#pragma unroll
      for (int dn = 0; dn < 4; ++dn) {
        const int vrow = dn * 16 + lr;
        const int ch = (2 * kn + (g >> 1)) ^ (vrow & 7);  // 16B-chunk swizzle
        const bf16x4 vf = *(const bf16x4*)
            &Vs[CUR][vrow * 64 + ch * 8 + ((g & 1) << 2)];
        oacc[dn] = mfma16k(pa[kn], vf, oacc[dn]);
      }
    }
    __builtin_amdgcn_s_setprio(0);

    VMCNT0();
    BARRIER();
  };

  stage(0, 0);
  VMCNT0();
  BARRIER();

#pragma unroll
  for (int kp = 0; kp < 8; ++kp) {
    tile(2 * kp, std::integral_constant<int, 0>{});
    tile(2 * kp + 1, std::integral_constant<int, 1>{});
  }

  // ---- epilogue: out[b][q][h*64+d] = oacc / l ----
  const int b = hb >> 4, h = hb & 15;
  float rl[4];
#pragma unroll
  for (int r = 0; r < 4; ++r) rl[r] = 1.0f / lacc[r];
#pragma unroll
  for (int dn = 0; dn < 4; ++dn) {
#pragma unroll
    for (int r = 0; r < 4; ++r) {
      const int q = (qt << 7) + (w << 4) + (g << 2) + r;
      const int d = dn * 16 + lr;
      O[((size_t)(b * 1024 + q) << 10) + h * 64 + d] = oacc[dn][r] * rl[r];
    }
  }
}

// ---------------------------------------------------------------------------
extern "C" void kernel_launch(void* const* d_in, const int* in_sizes, int n_in,
                              void* d_out, int out_size, void* d_ws,
                              size_t ws_size, hipStream_t stream) {
  const float* x   = (const float*)d_in[0];
  const float* Wq  = (const float*)d_in[1];
  const float* bq  = (const float*)d_in[2];
  const float* Wk  = (const float*)d_in[3];
  const float* bk  = (const float*)d_in[4];
  const float* Wv  = (const float*)d_in[5];
  const float* bv  = (const float*)d_in[6];
  const float* Wq2 = (const float*)d_in[7];
  const float* bq2 = (const float*)d_in[8];
  const float* Wk2 = (const float*)d_in[9];
  const float* bk2 = (const float*)d_in[10];
  const float* Wv2 = (const float*)d_in[11];
  const float* bv2 = (const float*)d_in[12];

  char* ws = (char*)d_ws;
  short* xbf = (short*)ws;                      // 8 MB
  short* wbf = (short*)(ws + 8388608);          // 12 MB
  short* qkv = (short*)(ws + 20971520);         // 6 x 8 MB

  convert_k<<<2048, 256, 0, stream>>>(x, Wq, Wk, Wv, Wq2, Wk2, Wv2, xbf, wbf);
  proj_gemm192<<<512, 512, 0, stream>>>(xbf, wbf, bq, bk, bv, bq2, bk2,
                                        bv2, qkv);
  attn_k<<<1024, 512, 0, stream>>>(qkv, (float*)d_out);
}

// Round 18
// 149.536 us; speedup vs baseline: 1.2695x; 1.0233x over previous
//
#include <hip/hip_runtime.h>

// ---------------------------------------------------------------------------
// SelfAttention (dual cross-attention): B=4, S=1024, HID=1024, NH=16, DH=64
//   q1,k1,v1,q2,k2,v2 = x @ W*.T + b*   (bf16 MFMA, f32 accum)
//   out5 = attn(q1,k2,v2), out3 = attn(q2,k1,v1)
// ---------------------------------------------------------------------------

typedef __attribute__((ext_vector_type(8))) short bf16x8;
typedef __attribute__((ext_vector_type(4))) short bf16x4;
typedef __attribute__((ext_vector_type(4))) float f32x4;
typedef __attribute__((ext_vector_type(4))) short s16x4;

#define MFMA16(a, b, c) __builtin_amdgcn_mfma_f32_16x16x32_bf16(a, b, c, 0, 0, 0)
#define BARRIER() asm volatile("s_barrier" ::: "memory")
#define VMCNT0() asm volatile("s_waitcnt vmcnt(0)" ::: "memory")

__device__ __forceinline__ f32x4 mfma16k(bf16x4 a, bf16x4 b, f32x4 c) {
#if __has_builtin(__builtin_amdgcn_mfma_f32_16x16x16bf16_1k)
  return __builtin_amdgcn_mfma_f32_16x16x16bf16_1k(a, b, c, 0, 0, 0);
#elif __has_builtin(__builtin_amdgcn_mfma_f32_16x16x16_bf16)
  return __builtin_amdgcn_mfma_f32_16x16x16_bf16(a, b, c, 0, 0, 0);
#else
  asm volatile("v_mfma_f32_16x16x16_bf16 %0, %1, %2, %0"
               : "+v"(c) : "v"(a), "v"(b));
  return c;
#endif
}

__device__ __forceinline__ unsigned short f2bf(float f) {
  unsigned u = __float_as_uint(f);
  u = (u + 0x7fffu + ((u >> 16) & 1u)) >> 16;  // RNE
  return (unsigned short)u;
}

__device__ __forceinline__ unsigned cvt_pk_bf16(float lo, float hi) {
  unsigned r;
  asm("v_cvt_pk_bf16_f32 %0, %1, %2" : "=v"(r) : "v"(lo), "v"(hi));
  return r;
}

__device__ __forceinline__ void gll16(const void* g, void* l) {
  __builtin_amdgcn_global_load_lds(
      (const __attribute__((address_space(1))) unsigned int*)g,
      (__attribute__((address_space(3))) unsigned int*)l, 16, 0, 0);
}

// ---------------------------------------------------------------------------
// Kernel 1: f32 -> bf16 conversion of x (4M) and the 6 weight matrices
// (6x1M). Grid-stride over 2.62M float4 slots, 2048 blocks (G11).
// ---------------------------------------------------------------------------
__global__ __launch_bounds__(256) void convert_k(
    const float* __restrict__ x,
    const float* __restrict__ W0, const float* __restrict__ W1,
    const float* __restrict__ W2, const float* __restrict__ W3,
    const float* __restrict__ W4, const float* __restrict__ W5,
    short* __restrict__ xbf, short* __restrict__ wbf) {
  const int total = (10 << 20) >> 2;  // 2.62M vec4 slots
  for (int tid = blockIdx.x * 256 + threadIdx.x; tid < total;
       tid += 2048 * 256) {
    const int e = tid << 2;
    const float* src;
    short* dst;
    int off;
    if (e < (4 << 20)) {
      src = x; dst = xbf; off = e;
    } else {
      const int j = e - (4 << 20);
      const int wsel = j >> 20;
      off = j & ((1 << 20) - 1);
      src = (wsel == 0) ? W0 : (wsel == 1) ? W1 : (wsel == 2) ? W2
          : (wsel == 3) ? W3 : (wsel == 4) ? W4 : W5;
      dst = wbf + ((size_t)wsel << 20);
    }
    const float4 v = *(const float4*)(src + off);
    s16x4 o;
    o.x = (short)f2bf(v.x);
    o.y = (short)f2bf(v.y);
    o.z = (short)f2bf(v.z);
    o.w = (short)f2bf(v.w);
    *(s16x4*)(dst + off) = o;
  }
}

// ---------------------------------------------------------------------------
// Kernel 2: projection GEMM, 128x192 block, BK=64, 256 thr (4 waves 2Mx2N,
// wave-tile 64x96) — r12's exact proven components (swizzle, 2-phase fenced
// schedule, dribbled stage, vmcnt(0) certify) at a tile that fits 2
// blocks/CU: LDS 80 KB, launch_bounds(256,2). Grid 1024 = 32m x (8xcd x 4n)
// = exact 2 co-residency rounds; 1.5 MB B per XCD L2-hot; A-panel reused x4
// within XCD. The co-resident block fills r12's 53% dual-idle stalls (m114).
// ---------------------------------------------------------------------------
__global__ __launch_bounds__(256, 2) void proj_t2(
    const short* __restrict__ Ag, const short* __restrict__ Wall,
    const float* __restrict__ bq, const float* __restrict__ bk,
    const float* __restrict__ bv, const float* __restrict__ bq2,
    const float* __restrict__ bk2, const float* __restrict__ bv2,
    short* __restrict__ qkv) {
  __shared__ __align__(16) short As[2][8192];   // 128 x 64
  __shared__ __align__(16) short Bs[2][12288];  // 192 x 64

  const int bid = blockIdx.x;             // 1024
  const int xcd = bid & 7, i = bid >> 3;  // 128 per XCD
  const int ns = i >> 5, mb = i & 31;     // 4 n-panels/XCD
  const int nbase = (xcd * 4 + ns) * 192;
  const int m0 = mb << 7;

  const int t = threadIdx.x, lane = t & 63, w = t >> 6;
  const int g = lane >> 4, lr = lane & 15;
  const int wr = w >> 1, wc = w & 1;      // 2M x 2N waves; wave C = 64x96

  f32x4 acc[4][6] = {};

  // stage helpers: linear LDS dest, inverse-chunk-swizzled global source
  auto stage_a = [&](int T) {  // A 128 rows, 4 instr/thread
#pragma unroll
    for (int ld = 0; ld < 4; ++ld) {
      const int slot = (ld << 8) + t;
      const int rr = slot >> 3;
      const int gc = (slot & 7) ^ (rr & 7);
      gll16(Ag + (size_t)(m0 + rr) * 1024 + (T << 6) + (gc << 3),
            &As[T & 1][slot * 8]);
    }
  };
  auto stage_b = [&](int T) {  // B 192 rows, 6 instr/thread
#pragma unroll
    for (int ld = 0; ld < 6; ++ld) {
      const int slot = (ld << 8) + t;
      const int rr = slot >> 3;
      const int gc = (slot & 7) ^ (rr & 7);
      gll16(Wall + (size_t)(nbase + rr) * 1024 + (T << 6) + (gc << 3),
            &Bs[T & 1][slot * 8]);
    }
  };

  // prologue: tile 0 -> buf0
  stage_a(0); stage_b(0);
  VMCNT0();
  BARRIER();

#define LOAD_A(KK, TB)                                                    \
  _Pragma("unroll") for (int mi = 0; mi < 4; ++mi) {                      \
    const int rA = wr * 64 + mi * 16 + lr;                                \
    af[mi] = *(const bf16x8*)                                             \
        &As[TB][rA * 64 + ((((KK) * 4 + g) ^ (rA & 7)) << 3)];            \
  }
#define LOAD_B(KK, TB)                                                    \
  _Pragma("unroll") for (int nj = 0; nj < 6; ++nj) {                      \
    const int rB = wc * 96 + nj * 16 + lr;                                \
    bf[nj] = *(const bf16x8*)                                             \
        &Bs[TB][rB * 64 + ((((KK) * 4 + g) ^ (rB & 7)) << 3)];            \
  }
#define MFMA_C()                                                          \
  __builtin_amdgcn_s_setprio(1);                                          \
  _Pragma("unroll") for (int mi = 0; mi < 4; ++mi)                        \
    _Pragma("unroll") for (int nj = 0; nj < 6; ++nj)                      \
      acc[mi][nj] = MFMA16(af[mi], bf[nj], acc[mi][nj]);                  \
  __builtin_amdgcn_s_setprio(0);

  for (int T = 0; T < 16; ++T) {
    const int C = T & 1;
    const bool DV = T < 15;
    bf16x8 af[4], bf[6];
    { // phase 1: kk0 (10 ds); dribble next tile's A (4 gll16)
      LOAD_A(0, C); LOAD_B(0, C);
      if (DV) stage_a(T + 1);
      BARRIER();
      MFMA_C();
      BARRIER();
    }
    { // phase 2: kk1 (10 ds); dribble next tile's B (6 gll16); certify
      LOAD_A(1, C); LOAD_B(1, C);
      if (DV) stage_b(T + 1);
      BARRIER();
      MFMA_C();
      VMCNT0();
      BARRIER();
    }
  }

#undef LOAD_A
#undef LOAD_B
#undef MFMA_C

  // ---- epilogue: bias + bf16 pack into attention layouts (per-column p) ----
#pragma unroll
  for (int nj = 0; nj < 6; ++nj) {
    const int nn = nbase + wc * 96 + nj * 16 + lr;
    const int p = nn >> 10, nl = nn & 1023;
    const float* bp = (p == 0) ? bq : (p == 1) ? bk : (p == 2) ? bv
                    : (p == 3) ? bq2 : (p == 4) ? bk2 : bv2;
    const float bb = bp[nl];
    const int h = nl >> 6, d = nl & 63;
    const int pt = (p == 0 || p == 3) ? 0 : (p == 1 || p == 4) ? 1 : 2;
    unsigned short* dst = (unsigned short*)qkv + ((size_t)p << 22);
#pragma unroll
    for (int mi = 0; mi < 4; ++mi) {
#pragma unroll
      for (int r = 0; r < 4; ++r) {
        const int m = m0 + wr * 64 + mi * 16 + (g << 2) + r;
        const int b = m >> 10, s = m & 1023;
        const unsigned short val = f2bf(acc[mi][nj][r] + bb);
        size_t idx;
        if (pt == 0) {
          idx = ((size_t)(((b << 4) + h) * 1024 + s) << 6) + d;
        } else if (pt == 1) {
          const int d2 = (d & 7) | (((d >> 3) ^ (s & 7)) << 3);
          idx = ((size_t)(((b << 4) + h) * 1024 + s) << 6) + d2;
        } else {
          const int tt = s >> 6, s2 = s & 63;
          const int s3 = (s2 & 7) | (((s2 >> 3) ^ (d & 7)) << 3);
          idx = ((size_t)((((b << 4) + h) * 16 + tt) * 64 + d) << 6) + s3;
        }
        dst[idx] = val;
      }
    }
  }
}

// ---------------------------------------------------------------------------
// Kernel 3: flash attention, swapped-QK^T in-register-P form; 128-row Q-tile
// (8 waves, 512 thr), double-buffered KV (32 KB -> 4 blocks/CU), KV loop
// unrolled x2 with literal buffer indices. Round-17 version verbatim.
// ---------------------------------------------------------------------------
__global__ __launch_bounds__(512) void attn_k(const short* __restrict__ qkv,
                                              float* __restrict__ out) {
  __shared__ __align__(16) short Ks[2][64 * 64];
  __shared__ __align__(16) short Vs[2][64 * 64];

  const int L = blockIdx.x;  // 1024 blocks
  const int xcd = L & 7, ss = L >> 3;   // ss 0..127
  const int qt = ss & 7, pg = ss >> 3;  // 8 q-tiles of 128 rows
  const int pp = xcd + (pg << 3);  // all q-tiles of a head share an XCD
  const int hb = pp & 63, dir = pp >> 6;

  const short* Q = qkv + ((size_t)(dir ? 3 : 0) << 22) + ((size_t)hb << 16);
  const short* K = qkv + ((size_t)(dir ? 1 : 4) << 22) + ((size_t)hb << 16);
  const short* V = qkv + ((size_t)(dir ? 2 : 5) << 22) + ((size_t)hb << 16);
  float* O = out + ((size_t)dir << 22);

  const int t = threadIdx.x, lane = t & 63, w = t >> 6;  // w 0..7
  const int g = lane >> 4, lr = lane & 15;

  const int qrow = (qt << 7) + (w << 4) + lr;
  bf16x8 qf[2];
  qf[0] = *(const bf16x8*)(Q + qrow * 64 + g * 8);
  qf[1] = *(const bf16x8*)(Q + qrow * 64 + 32 + g * 8);

  const bf16x4 ones4 = {0x3F80, 0x3F80, 0x3F80, 0x3F80};

  f32x4 oacc[4] = {};
  f32x4 lacc = {};
  float mrun = -3.0e38f;               // running max for q = lr (log2 units)
  const float CSC = 0.18033688f;       // (1/8) * log2(e)

  const int srow = t >> 3;             // staging row 0..63 (1 gll16/thread)
  const int scol = (t & 7) << 3;

  auto stage = [&](int kt, int buf) {
    gll16(K + (size_t)((kt << 6) + srow) * 64 + scol, &Ks[buf][w << 9]);
    gll16(V + (size_t)(kt << 12) + (size_t)srow * 64 + scol, &Vs[buf][w << 9]);
  };

  // one KV tile with compile-time buffer index CUR
  auto tile = [&](int kt, auto curc) {
    constexpr int CUR = decltype(curc)::value;
    if (kt < 15) stage(kt + 1, CUR ^ 1);

    // ---- S^T = K Q^T (swapped): lane gets P^T[k=kn*16+g*4+r][q=lr] ----
    f32x4 sc2[4] = {};
    __builtin_amdgcn_s_setprio(1);
#pragma unroll
    for (int dk = 0; dk < 2; ++dk) {
#pragma unroll
      for (int kn = 0; kn < 4; ++kn) {
        const int krow = kn * 16 + lr;
        const bf16x8 kf = *(const bf16x8*)
            &Ks[CUR][krow * 64 +
                     ((((dk << 6) + (g << 4)) ^ ((krow & 7) << 4)) >> 1)];
        sc2[kn] = MFMA16(kf, qf[dk], sc2[kn]);
      }
    }
    __builtin_amdgcn_s_setprio(0);

    // ---- softmax (per-lane scalar state, defer-max) ----
    float tm = fmaxf(fmaxf(fmaxf(sc2[0][0], sc2[0][1]),
                           fmaxf(sc2[0][2], sc2[0][3])),
                     fmaxf(fmaxf(sc2[1][0], sc2[1][1]),
                           fmaxf(sc2[1][2], sc2[1][3])));
    tm = fmaxf(tm, fmaxf(fmaxf(fmaxf(sc2[2][0], sc2[2][1]),
                               fmaxf(sc2[2][2], sc2[2][3])),
                         fmaxf(fmaxf(sc2[3][0], sc2[3][1]),
                               fmaxf(sc2[3][2], sc2[3][3]))));
    const bool ok = __all(fmaf(tm, CSC, -mrun) <= 8.0f);
    if (!ok) {
      float t2 = fmaxf(tm, __shfl_xor(tm, 16));
      t2 = fmaxf(t2, __shfl_xor(t2, 32));
      const float mnew = fmaxf(mrun, t2 * CSC);
      const float scq = exp2f(mrun - mnew);  // scale for q = lr
      mrun = mnew;
#pragma unroll
      for (int r = 0; r < 4; ++r) {
        const float sr = __shfl(scq, (g << 2) + r);  // scale for q = g*4+r
        lacc[r] *= sr;
#pragma unroll
        for (int dn = 0; dn < 4; ++dn) oacc[dn][r] *= sr;
      }
    }

    bf16x4 pa[4];
#pragma unroll
    for (int kn = 0; kn < 4; ++kn) {
      const float p0 = exp2f(fmaf(sc2[kn][0], CSC, -mrun));
      const float p1 = exp2f(fmaf(sc2[kn][1], CSC, -mrun));
      const float p2 = exp2f(fmaf(sc2[kn][2], CSC, -mrun));
      const float p3 = exp2f(fmaf(sc2[kn][3], CSC, -mrun));
      union { unsigned u[2]; bf16x4 v; } pk;
      pk.u[0] = cvt_pk_bf16(p0, p1);
      pk.u[1] = cvt_pk_bf16(p2, p3);
      pa[kn] = pk.v;
    }

    // ---- O += P V ; l += P @ ones  (K=16 MFMAs, P straight from regs) ----
    __builtin_amdgcn_s_setprio(1);
#pragma unroll
    for (int kn = 0; kn < 4; ++kn) {
      lacc = mfma16k(pa[kn], ones4, lacc);
#pragma unroll
      for (int dn = 0; dn < 4; ++dn) {
        const int vrow = dn * 16 + lr;
        const int ch = (2 * kn + (g >> 1)) ^ (vrow & 7);  // 16B-chunk swizzle
        const bf16x4 vf = *(const bf16x4*)
            &Vs[CUR][vrow * 64 + ch * 8 + ((g & 1) << 2)];
        oacc[dn] = mfma16k(pa[kn], vf, oacc[dn]);
      }
    }
    __builtin_amdgcn_s_setprio(0);

    VMCNT0();
    BARRIER();
  };

  stage(0, 0);
  VMCNT0();
  BARRIER();

#pragma unroll
  for (int kp = 0; kp < 8; ++kp) {
    tile(2 * kp, std::integral_constant<int, 0>{});
    tile(2 * kp + 1, std::integral_constant<int, 1>{});
  }

  // ---- epilogue: out[b][q][h*64+d] = oacc / l ----
  const int b = hb >> 4, h = hb & 15;
  float rl[4];
#pragma unroll
  for (int r = 0; r < 4; ++r) rl[r] = 1.0f / lacc[r];
#pragma unroll
  for (int dn = 0; dn < 4; ++dn) {
#pragma unroll
    for (int r = 0; r < 4; ++r) {
      const int q = (qt << 7) + (w << 4) + (g << 2) + r;
      const int d = dn * 16 + lr;
      O[((size_t)(b * 1024 + q) << 10) + h * 64 + d] = oacc[dn][r] * rl[r];
    }
  }
}

// ---------------------------------------------------------------------------
extern "C" void kernel_launch(void* const* d_in, const int* in_sizes, int n_in,
                              void* d_out, int out_size, void* d_ws,
                              size_t ws_size, hipStream_t stream) {
  const float* x   = (const float*)d_in[0];
  const float* Wq  = (const float*)d_in[1];
  const float* bq  = (const float*)d_in[2];
  const float* Wk  = (const float*)d_in[3];
  const float* bk  = (const float*)d_in[4];
  const float* Wv  = (const float*)d_in[5];
  const float* bv  = (const float*)d_in[6];
  const float* Wq2 = (const float*)d_in[7];
  const float* bq2 = (const float*)d_in[8];
  const float* Wk2 = (const float*)d_in[9];
  const float* bk2 = (const float*)d_in[10];
  const float* Wv2 = (const float*)d_in[11];
  const float* bv2 = (const float*)d_in[12];

  char* ws = (char*)d_ws;
  short* xbf = (short*)ws;                      // 8 MB
  short* wbf = (short*)(ws + 8388608);          // 12 MB
  short* qkv = (short*)(ws + 20971520);         // 6 x 8 MB

  convert_k<<<2048, 256, 0, stream>>>(x, Wq, Wk, Wv, Wq2, Wk2, Wv2, xbf, wbf);
  proj_t2<<<1024, 256, 0, stream>>>(xbf, wbf, bq, bk, bv, bq2, bk2,
                                    bv2, qkv);
  attn_k<<<1024, 512, 0, stream>>>(qkv, (float*)d_out);
}

// Round 19
// 144.907 us; speedup vs baseline: 1.3101x; 1.0319x over previous
//
#include <hip/hip_runtime.h>

// ---------------------------------------------------------------------------
// SelfAttention (dual cross-attention): B=4, S=1024, HID=1024, NH=16, DH=64
//   q1,k1,v1,q2,k2,v2 = x @ W*.T + b*   (bf16 MFMA, f32 accum)
//   out5 = attn(q1,k2,v2), out3 = attn(q2,k1,v1)
// ---------------------------------------------------------------------------

typedef __attribute__((ext_vector_type(8))) short bf16x8;
typedef __attribute__((ext_vector_type(4))) short bf16x4;
typedef __attribute__((ext_vector_type(4))) float f32x4;
typedef __attribute__((ext_vector_type(4))) short s16x4;

#define MFMA16(a, b, c) __builtin_amdgcn_mfma_f32_16x16x32_bf16(a, b, c, 0, 0, 0)
#define BARRIER() asm volatile("s_barrier" ::: "memory")
#define VMCNT0() asm volatile("s_waitcnt vmcnt(0)" ::: "memory")

__device__ __forceinline__ f32x4 mfma16k(bf16x4 a, bf16x4 b, f32x4 c) {
#if __has_builtin(__builtin_amdgcn_mfma_f32_16x16x16bf16_1k)
  return __builtin_amdgcn_mfma_f32_16x16x16bf16_1k(a, b, c, 0, 0, 0);
#elif __has_builtin(__builtin_amdgcn_mfma_f32_16x16x16_bf16)
  return __builtin_amdgcn_mfma_f32_16x16x16_bf16(a, b, c, 0, 0, 0);
#else
  asm volatile("v_mfma_f32_16x16x16_bf16 %0, %1, %2, %0"
               : "+v"(c) : "v"(a), "v"(b));
  return c;
#endif
}

__device__ __forceinline__ unsigned short f2bf(float f) {
  unsigned u = __float_as_uint(f);
  u = (u + 0x7fffu + ((u >> 16) & 1u)) >> 16;  // RNE
  return (unsigned short)u;
}

__device__ __forceinline__ unsigned cvt_pk_bf16(float lo, float hi) {
  unsigned r;
  asm("v_cvt_pk_bf16_f32 %0, %1, %2" : "=v"(r) : "v"(lo), "v"(hi));
  return r;
}

__device__ __forceinline__ void gll16(const void* g, void* l) {
  __builtin_amdgcn_global_load_lds(
      (const __attribute__((address_space(1))) unsigned int*)g,
      (__attribute__((address_space(3))) unsigned int*)l, 16, 0, 0);
}

// ---------------------------------------------------------------------------
// Kernel 1: f32 -> bf16 conversion of x (4M) and the 6 weight matrices
// (6x1M). Grid-stride over 2.62M float4 slots, 2048 blocks (G11).
// ---------------------------------------------------------------------------
__global__ __launch_bounds__(256) void convert_k(
    const float* __restrict__ x,
    const float* __restrict__ W0, const float* __restrict__ W1,
    const float* __restrict__ W2, const float* __restrict__ W3,
    const float* __restrict__ W4, const float* __restrict__ W5,
    short* __restrict__ xbf, short* __restrict__ wbf) {
  const int total = (10 << 20) >> 2;  // 2.62M vec4 slots
  for (int tid = blockIdx.x * 256 + threadIdx.x; tid < total;
       tid += 2048 * 256) {
    const int e = tid << 2;
    const float* src;
    short* dst;
    int off;
    if (e < (4 << 20)) {
      src = x; dst = xbf; off = e;
    } else {
      const int j = e - (4 << 20);
      const int wsel = j >> 20;
      off = j & ((1 << 20) - 1);
      src = (wsel == 0) ? W0 : (wsel == 1) ? W1 : (wsel == 2) ? W2
          : (wsel == 3) ? W3 : (wsel == 4) ? W4 : W5;
      dst = wbf + ((size_t)wsel << 20);
    }
    const float4 v = *(const float4*)(src + off);
    s16x4 o;
    o.x = (short)f2bf(v.x);
    o.y = (short)f2bf(v.y);
    o.z = (short)f2bf(v.z);
    o.w = (short)f2bf(v.w);
    *(s16x4*)(dst + off) = o;
  }
}

// ---------------------------------------------------------------------------
// Kernel 2: projection GEMM, 128x192 block, BK=64, 256 thr (4 waves 2Mx2N,
// wave-tile 64x96), 2 blocks/CU (LDS 80 KB). r18 structure; r19 changes:
// (a) index split ns=i&3 (inner) so each dispatch round holds 4 B-panels +
//     16 A-panels (5.5 MB/XCD, A reused x4 back-to-back) instead of 8.75 MB;
// (b) V epilogue adds sub-half swizzle (bit2 of within-chunk short index
//     XOR'd with (d>>3)&1) so attn's 8B V-reads spread across all 32 banks.
// ---------------------------------------------------------------------------
__global__ __launch_bounds__(256, 2) void proj_t2(
    const short* __restrict__ Ag, const short* __restrict__ Wall,
    const float* __restrict__ bq, const float* __restrict__ bk,
    const float* __restrict__ bv, const float* __restrict__ bq2,
    const float* __restrict__ bk2, const float* __restrict__ bv2,
    short* __restrict__ qkv) {
  __shared__ __align__(16) short As[2][8192];   // 128 x 64
  __shared__ __align__(16) short Bs[2][12288];  // 192 x 64

  const int bid = blockIdx.x;             // 1024
  const int xcd = bid & 7, i = bid >> 3;  // 128 per XCD
  const int ns = i & 3, mb = i >> 2;      // ns inner: A-panel reused x4
  const int nbase = (xcd * 4 + ns) * 192;
  const int m0 = mb << 7;

  const int t = threadIdx.x, lane = t & 63, w = t >> 6;
  const int g = lane >> 4, lr = lane & 15;
  const int wr = w >> 1, wc = w & 1;      // 2M x 2N waves; wave C = 64x96

  f32x4 acc[4][6] = {};

  // stage helpers: linear LDS dest, inverse-chunk-swizzled global source
  auto stage_a = [&](int T) {  // A 128 rows, 4 instr/thread
#pragma unroll
    for (int ld = 0; ld < 4; ++ld) {
      const int slot = (ld << 8) + t;
      const int rr = slot >> 3;
      const int gc = (slot & 7) ^ (rr & 7);
      gll16(Ag + (size_t)(m0 + rr) * 1024 + (T << 6) + (gc << 3),
            &As[T & 1][slot * 8]);
    }
  };
  auto stage_b = [&](int T) {  // B 192 rows, 6 instr/thread
#pragma unroll
    for (int ld = 0; ld < 6; ++ld) {
      const int slot = (ld << 8) + t;
      const int rr = slot >> 3;
      const int gc = (slot & 7) ^ (rr & 7);
      gll16(Wall + (size_t)(nbase + rr) * 1024 + (T << 6) + (gc << 3),
            &Bs[T & 1][slot * 8]);
    }
  };

  // prologue: tile 0 -> buf0
  stage_a(0); stage_b(0);
  VMCNT0();
  BARRIER();

#define LOAD_A(KK, TB)                                                    \
  _Pragma("unroll") for (int mi = 0; mi < 4; ++mi) {                      \
    const int rA = wr * 64 + mi * 16 + lr;                                \
    af[mi] = *(const bf16x8*)                                             \
        &As[TB][rA * 64 + ((((KK) * 4 + g) ^ (rA & 7)) << 3)];            \
  }
#define LOAD_B(KK, TB)                                                    \
  _Pragma("unroll") for (int nj = 0; nj < 6; ++nj) {                      \
    const int rB = wc * 96 + nj * 16 + lr;                                \
    bf[nj] = *(const bf16x8*)                                             \
        &Bs[TB][rB * 64 + ((((KK) * 4 + g) ^ (rB & 7)) << 3)];            \
  }
#define MFMA_C()                                                          \
  __builtin_amdgcn_s_setprio(1);                                          \
  _Pragma("unroll") for (int mi = 0; mi < 4; ++mi)                        \
    _Pragma("unroll") for (int nj = 0; nj < 6; ++nj)                      \
      acc[mi][nj] = MFMA16(af[mi], bf[nj], acc[mi][nj]);                  \
  __builtin_amdgcn_s_setprio(0);

  for (int T = 0; T < 16; ++T) {
    const int C = T & 1;
    const bool DV = T < 15;
    bf16x8 af[4], bf[6];
    { // phase 1: kk0 (10 ds); dribble next tile's A (4 gll16)
      LOAD_A(0, C); LOAD_B(0, C);
      if (DV) stage_a(T + 1);
      BARRIER();
      MFMA_C();
      BARRIER();
    }
    { // phase 2: kk1 (10 ds); dribble next tile's B (6 gll16); certify
      LOAD_A(1, C); LOAD_B(1, C);
      if (DV) stage_b(T + 1);
      BARRIER();
      MFMA_C();
      VMCNT0();
      BARRIER();
    }
  }

#undef LOAD_A
#undef LOAD_B
#undef MFMA_C

  // ---- epilogue: bias + bf16 pack into attention layouts (per-column p) ----
#pragma unroll
  for (int nj = 0; nj < 6; ++nj) {
    const int nn = nbase + wc * 96 + nj * 16 + lr;
    const int p = nn >> 10, nl = nn & 1023;
    const float* bp = (p == 0) ? bq : (p == 1) ? bk : (p == 2) ? bv
                    : (p == 3) ? bq2 : (p == 4) ? bk2 : bv2;
    const float bb = bp[nl];
    const int h = nl >> 6, d = nl & 63;
    const int pt = (p == 0 || p == 3) ? 0 : (p == 1 || p == 4) ? 1 : 2;
    unsigned short* dst = (unsigned short*)qkv + ((size_t)p << 22);
#pragma unroll
    for (int mi = 0; mi < 4; ++mi) {
#pragma unroll
      for (int r = 0; r < 4; ++r) {
        const int m = m0 + wr * 64 + mi * 16 + (g << 2) + r;
        const int b = m >> 10, s = m & 1023;
        const unsigned short val = f2bf(acc[mi][nj][r] + bb);
        size_t idx;
        if (pt == 0) {
          idx = ((size_t)(((b << 4) + h) * 1024 + s) << 6) + d;
        } else if (pt == 1) {
          const int d2 = (d & 7) | (((d >> 3) ^ (s & 7)) << 3);
          idx = ((size_t)(((b << 4) + h) * 1024 + s) << 6) + d2;
        } else {
          const int tt = s >> 6, s2 = s & 63;
          // chunk swizzle by d&7; sub-half (bit2) swizzle by (d>>3)&1 so
          // attn's 8B reads use all 32 banks (lanes g&1=0 vs lr>=8 split).
          const int w2 = (s2 & 7) ^ (((d >> 3) & 1) << 2);
          const int s3 = w2 | (((s2 >> 3) ^ (d & 7)) << 3);
          idx = ((size_t)((((b << 4) + h) * 16 + tt) * 64 + d) << 6) + s3;
        }
        dst[idx] = val;
      }
    }
  }
}

// ---------------------------------------------------------------------------
// Kernel 3: flash attention, swapped-QK^T in-register-P form; 128-row Q-tile
// (8 waves, 512 thr), double-buffered KV (32 KB -> 4 blocks/CU), KV loop
// unrolled x2 with literal buffer indices. r19: V-read sub-half swizzle
// matches proj's new V layout -> 8B reads conflict-free (was 2-way, 8.4e6).
// ---------------------------------------------------------------------------
__global__ __launch_bounds__(512) void attn_k(const short* __restrict__ qkv,
                                              float* __restrict__ out) {
  __shared__ __align__(16) short Ks[2][64 * 64];
  __shared__ __align__(16) short Vs[2][64 * 64];

  const int L = blockIdx.x;  // 1024 blocks
  const int xcd = L & 7, ss = L >> 3;   // ss 0..127
  const int qt = ss & 7, pg = ss >> 3;  // 8 q-tiles of 128 rows
  const int pp = xcd + (pg << 3);  // all q-tiles of a head share an XCD
  const int hb = pp & 63, dir = pp >> 6;

  const short* Q = qkv + ((size_t)(dir ? 3 : 0) << 22) + ((size_t)hb << 16);
  const short* K = qkv + ((size_t)(dir ? 1 : 4) << 22) + ((size_t)hb << 16);
  const short* V = qkv + ((size_t)(dir ? 2 : 5) << 22) + ((size_t)hb << 16);
  float* O = out + ((size_t)dir << 22);

  const int t = threadIdx.x, lane = t & 63, w = t >> 6;  // w 0..7
  const int g = lane >> 4, lr = lane & 15;

  const int qrow = (qt << 7) + (w << 4) + lr;
  bf16x8 qf[2];
  qf[0] = *(const bf16x8*)(Q + qrow * 64 + g * 8);
  qf[1] = *(const bf16x8*)(Q + qrow * 64 + 32 + g * 8);

  const bf16x4 ones4 = {0x3F80, 0x3F80, 0x3F80, 0x3F80};

  f32x4 oacc[4] = {};
  f32x4 lacc = {};
  float mrun = -3.0e38f;               // running max for q = lr (log2 units)
  const float CSC = 0.18033688f;       // (1/8) * log2(e)

  const int srow = t >> 3;             // staging row 0..63 (1 gll16/thread)
  const int scol = (t & 7) << 3;

  auto stage = [&](int kt, int buf) {
    gll16(K + (size_t)((kt << 6) + srow) * 64 + scol, &Ks[buf][w << 9]);
    gll16(V + (size_t)(kt << 12) + (size_t)srow * 64 + scol, &Vs[buf][w << 9]);
  };

  // one KV tile with compile-time buffer index CUR
  auto tile = [&](int kt, auto curc) {
    constexpr int CUR = decltype(curc)::value;
    if (kt < 15) stage(kt + 1, CUR ^ 1);

    // ---- S^T = K Q^T (swapped): lane gets P^T[k=kn*16+g*4+r][q=lr] ----
    f32x4 sc2[4] = {};
    __builtin_amdgcn_s_setprio(1);
#pragma unroll
    for (int dk = 0; dk < 2; ++dk) {
#pragma unroll
      for (int kn = 0; kn < 4; ++kn) {
        const int krow = kn * 16 + lr;
        const bf16x8 kf = *(const bf16x8*)
            &Ks[CUR][krow * 64 +
                     ((((dk << 6) + (g << 4)) ^ ((krow & 7) << 4)) >> 1)];
        sc2[kn] = MFMA16(kf, qf[dk], sc2[kn]);
      }
    }
    __builtin_amdgcn_s_setprio(0);

    // ---- softmax (per-lane scalar state, defer-max) ----
    float tm = fmaxf(fmaxf(fmaxf(sc2[0][0], sc2[0][1]),
                           fmaxf(sc2[0][2], sc2[0][3])),
                     fmaxf(fmaxf(sc2[1][0], sc2[1][1]),
                           fmaxf(sc2[1][2], sc2[1][3])));
    tm = fmaxf(tm, fmaxf(fmaxf(fmaxf(sc2[2][0], sc2[2][1]),
                               fmaxf(sc2[2][2], sc2[2][3])),
                         fmaxf(fmaxf(sc2[3][0], sc2[3][1]),
                               fmaxf(sc2[3][2], sc2[3][3]))));
    const bool ok = __all(fmaf(tm, CSC, -mrun) <= 8.0f);
    if (!ok) {
      float t2 = fmaxf(tm, __shfl_xor(tm, 16));
      t2 = fmaxf(t2, __shfl_xor(t2, 32));
      const float mnew = fmaxf(mrun, t2 * CSC);
      const float scq = exp2f(mrun - mnew);  // scale for q = lr
      mrun = mnew;
#pragma unroll
      for (int r = 0; r < 4; ++r) {
        const float sr = __shfl(scq, (g << 2) + r);  // scale for q = g*4+r
        lacc[r] *= sr;
#pragma unroll
        for (int dn = 0; dn < 4; ++dn) oacc[dn][r] *= sr;
      }
    }

    bf16x4 pa[4];
#pragma unroll
    for (int kn = 0; kn < 4; ++kn) {
      const float p0 = exp2f(fmaf(sc2[kn][0], CSC, -mrun));
      const float p1 = exp2f(fmaf(sc2[kn][1], CSC, -mrun));
      const float p2 = exp2f(fmaf(sc2[kn][2], CSC, -mrun));
      const float p3 = exp2f(fmaf(sc2[kn][3], CSC, -mrun));
      union { unsigned u[2]; bf16x4 v; } pk;
      pk.u[0] = cvt_pk_bf16(p0, p1);
      pk.u[1] = cvt_pk_bf16(p2, p3);
      pa[kn] = pk.v;
    }

    // ---- O += P V ; l += P @ ones  (K=16 MFMAs, P straight from regs) ----
    __builtin_amdgcn_s_setprio(1);
#pragma unroll
    for (int kn = 0; kn < 4; ++kn) {
      lacc = mfma16k(pa[kn], ones4, lacc);
#pragma unroll
      for (int dn = 0; dn < 4; ++dn) {
        const int vrow = dn * 16 + lr;
        const int ch = (2 * kn + (g >> 1)) ^ (vrow & 7);  // 16B-chunk swizzle
        const int sub = (((g & 1) ^ ((lr >> 3) & 1)) << 2);  // 8B sub-half
        const bf16x4 vf = *(const bf16x4*)
            &Vs[CUR][vrow * 64 + ch * 8 + sub];
        oacc[dn] = mfma16k(pa[kn], vf, oacc[dn]);
      }
    }
    __builtin_amdgcn_s_setprio(0);

    VMCNT0();
    BARRIER();
  };

  stage(0, 0);
  VMCNT0();
  BARRIER();

#pragma unroll
  for (int kp = 0; kp < 8; ++kp) {
    tile(2 * kp, std::integral_constant<int, 0>{});
    tile(2 * kp + 1, std::integral_constant<int, 1>{});
  }

  // ---- epilogue: out[b][q][h*64+d] = oacc / l ----
  const int b = hb >> 4, h = hb & 15;
  float rl[4];
#pragma unroll
  for (int r = 0; r < 4; ++r) rl[r] = 1.0f / lacc[r];
#pragma unroll
  for (int dn = 0; dn < 4; ++dn) {
#pragma unroll
    for (int r = 0; r < 4; ++r) {
      const int q = (qt << 7) + (w << 4) + (g << 2) + r;
      const int d = dn * 16 + lr;
      O[((size_t)(b * 1024 + q) << 10) + h * 64 + d] = oacc[dn][r] * rl[r];
    }
  }
}

// ---------------------------------------------------------------------------
extern "C" void kernel_launch(void* const* d_in, const int* in_sizes, int n_in,
                              void* d_out, int out_size, void* d_ws,
                              size_t ws_size, hipStream_t stream) {
  const float* x   = (const float*)d_in[0];
  const float* Wq  = (const float*)d_in[1];
  const float* bq  = (const float*)d_in[2];
  const float* Wk  = (const float*)d_in[3];
  const float* bk  = (const float*)d_in[4];
  const float* Wv  = (const float*)d_in[5];
  const float* bv  = (const float*)d_in[6];
  const float* Wq2 = (const float*)d_in[7];
  const float* bq2 = (const float*)d_in[8];
  const float* Wk2 = (const float*)d_in[9];
  const float* bk2 = (const float*)d_in[10];
  const float* Wv2 = (const float*)d_in[11];
  const float* bv2 = (const float*)d_in[12];

  char* ws = (char*)d_ws;
  short* xbf = (short*)ws;                      // 8 MB
  short* wbf = (short*)(ws + 8388608);          // 12 MB
  short* qkv = (short*)(ws + 20971520);         // 6 x 8 MB

  convert_k<<<2048, 256, 0, stream>>>(x, Wq, Wk, Wv, Wq2, Wk2, Wv2, xbf, wbf);
  proj_t2<<<1024, 256, 0, stream>>>(xbf, wbf, bq, bk, bv, bq2, bk2,
                                    bv2, qkv);
  attn_k<<<1024, 512, 0, stream>>>(qkv, (float*)d_out);
}